// Round 2
// baseline (4112.266 us; speedup 1.0000x reference)
//
#include <hip/hip_runtime.h>
#include <hip/hip_bf16.h>
#include <math.h>

// Problem constants (from reference)
#define BGRAPH 8192
#define NPG 32
#define EPG 64
#define NNODE (BGRAPH * NPG)   // 262144
#define NEDGE (BGRAPH * EPG)   // 524288
#define CELLD 908
#define BN_EPS 1e-5f

// ---------------------------------------------------------------------------
// Zero a small buffer (replaces hipMemsetAsync for graph-capture safety)
// ---------------------------------------------------------------------------
__global__ void zero_buf(float* __restrict__ p, int n)
{
    int i = blockIdx.x * blockDim.x + threadIdx.x;
    if (i < n) p[i] = 0.f;
}

// ---------------------------------------------------------------------------
// Generic tiled fp32 GEMM:  C[M,N] = A[M,K] @ W[K,N] + bias,  optional act.
// 64x64 tile, 256 threads, each thread computes 4x4. A and C must NOT alias.
// ---------------------------------------------------------------------------
#define TILE 64
#define TKK 16

__launch_bounds__(256)
__global__ void gemm_bias_act(const float* __restrict__ A, const float* __restrict__ W,
                              const float* __restrict__ bias, float* __restrict__ C,
                              int M, int K, int N, int act)
{
    __shared__ float As[TKK][TILE + 1];   // As[k][m]
    __shared__ float Ws[TKK][TILE + 1];   // Ws[k][n]
    int tid = threadIdx.x;      // 0..255
    int tx = tid & 15;          // n-dir
    int ty = tid >> 4;          // m-dir
    int m0 = blockIdx.x * TILE;
    int n0 = blockIdx.y * TILE;
    float acc[4][4] = {};

    for (int k0 = 0; k0 < K; k0 += TKK) {
        for (int i = tid; i < TILE * TKK; i += 256) {
            int mm = i / TKK, kk = i % TKK;
            int gm = m0 + mm, gk = k0 + kk;
            As[kk][mm] = (gm < M && gk < K) ? A[(size_t)gm * K + gk] : 0.f;
        }
        for (int i = tid; i < TKK * TILE; i += 256) {
            int kk = i / TILE, nn = i % TILE;
            int gk = k0 + kk, gn = n0 + nn;
            Ws[kk][nn] = (gk < K && gn < N) ? W[(size_t)gk * N + gn] : 0.f;
        }
        __syncthreads();
        #pragma unroll
        for (int kk = 0; kk < TKK; ++kk) {
            float a[4], b[4];
            #pragma unroll
            for (int i = 0; i < 4; ++i) a[i] = As[kk][ty * 4 + i];
            #pragma unroll
            for (int j = 0; j < 4; ++j) b[j] = Ws[kk][tx * 4 + j];
            #pragma unroll
            for (int i = 0; i < 4; ++i)
                #pragma unroll
                for (int j = 0; j < 4; ++j)
                    acc[i][j] += a[i] * b[j];
        }
        __syncthreads();
    }

    #pragma unroll
    for (int i = 0; i < 4; ++i) {
        int gm = m0 + ty * 4 + i;
        if (gm >= M) continue;
        #pragma unroll
        for (int j = 0; j < 4; ++j) {
            int gn = n0 + tx * 4 + j;
            if (gn >= N) continue;
            float v = acc[i][j] + bias[gn];
            if (act == 1) v = fmaxf(v, 0.f);
            C[(size_t)gm * N + gn] = v;
        }
    }
}

// ---------------------------------------------------------------------------
// N=128 GEMM, full output rows per block -> SAFE IN-PLACE (A may == C).
// Block: 64 rows x 128 cols; 256 threads; each thread 8x4 outputs.
// ---------------------------------------------------------------------------
__launch_bounds__(256)
__global__ void gemm_n128(const float* __restrict__ A, const float* __restrict__ W,
                          const float* __restrict__ bias, float* __restrict__ C,
                          int M, int K, int act)
{
    __shared__ float As[TKK][TILE + 1];    // [k][m]
    __shared__ float Ws[TKK][128 + 1];     // [k][n]
    int tid = threadIdx.x;
    int tx = tid & 31;          // cols tx*4 .. tx*4+3
    int ty = tid >> 5;          // rows ty*8 .. ty*8+7
    int m0 = blockIdx.x * TILE;
    float acc[8][4] = {};

    for (int k0 = 0; k0 < K; k0 += TKK) {
        for (int i = tid; i < TILE * TKK; i += 256) {
            int mm = i >> 4, kk = i & 15;
            int gm = m0 + mm, gk = k0 + kk;
            As[kk][mm] = (gm < M && gk < K) ? A[(size_t)gm * K + gk] : 0.f;
        }
        for (int i = tid; i < TKK * 128; i += 256) {
            int kk = i >> 7, nn = i & 127;
            int gk = k0 + kk;
            Ws[kk][nn] = (gk < K) ? W[(size_t)gk * 128 + nn] : 0.f;
        }
        __syncthreads();
        #pragma unroll
        for (int kk = 0; kk < TKK; ++kk) {
            float a[8], b[4];
            #pragma unroll
            for (int i = 0; i < 8; ++i) a[i] = As[kk][ty * 8 + i];
            #pragma unroll
            for (int j = 0; j < 4; ++j) b[j] = Ws[kk][tx * 4 + j];
            #pragma unroll
            for (int i = 0; i < 8; ++i)
                #pragma unroll
                for (int j = 0; j < 4; ++j)
                    acc[i][j] += a[i] * b[j];
        }
        __syncthreads();
    }

    #pragma unroll
    for (int i = 0; i < 8; ++i) {
        int gm = m0 + ty * 8 + i;
        if (gm >= M) continue;
        #pragma unroll
        for (int j = 0; j < 4; ++j) {
            int gn = tx * 4 + j;
            float v = acc[i][j] + bias[gn];
            if (act == 1) v = fmaxf(v, 0.f);
            C[(size_t)gm * 128 + gn] = v;
        }
    }
}

// ---------------------------------------------------------------------------
// Column stats: sums[c] += sum over rows, sumsq[c] += sum of squares.
// ---------------------------------------------------------------------------
__global__ void col_stats(const float* __restrict__ x, int M, int C,
                          float* __restrict__ sums, float* __restrict__ sumsq,
                          int prerelu)
{
    int col = blockIdx.x * blockDim.x + threadIdx.x;
    if (col >= C) return;
    float s = 0.f, ss = 0.f;
    for (int r = blockIdx.y; r < M; r += gridDim.y) {
        float v = x[(size_t)r * C + col];
        if (prerelu) v = fmaxf(v, 0.f);
        s += v; ss += v * v;
    }
    atomicAdd(&sums[col], s);
    atomicAdd(&sumsq[col], ss);
}

// ---------------------------------------------------------------------------
// BN normalize (training mode, biased var) + activation. In-place safe.
// act: 0=none, 1=relu, 2=elu. Optional pre-ReLU on input.
// ---------------------------------------------------------------------------
__global__ void bn_norm(const float* __restrict__ x, float* __restrict__ y,
                        int M, int C,
                        const float* __restrict__ sums, const float* __restrict__ sumsq,
                        int prerelu, int act)
{
    size_t idx = (size_t)blockIdx.x * blockDim.x + threadIdx.x;
    if (idx >= (size_t)M * C) return;
    int col = (int)(idx % C);
    float invM = 1.f / (float)M;
    float m = sums[col] * invM;
    float var = sumsq[col] * invM - m * m;
    float inv = rsqrtf(var + BN_EPS);
    float v = x[idx];
    if (prerelu) v = fmaxf(v, 0.f);
    v = (v - m) * inv;
    if (act == 1) v = fmaxf(v, 0.f);
    else if (act == 2) v = (v > 0.f) ? v : expm1f(v);
    y[idx] = v;
}

// ---------------------------------------------------------------------------
// GIN aggregation, one graph per block: out = x + segment_sum(x[src], dst).
// Block-local via LDS -> SAFE IN-PLACE (x may == out).
// ---------------------------------------------------------------------------
__global__ void gin_agg(const float* __restrict__ x, const int* __restrict__ src,
                        const int* __restrict__ dst, float* __restrict__ out, int F)
{
    extern __shared__ float lds[];
    __shared__ int es[EPG], ed[EPG];
    int g = blockIdx.x;
    int tid = threadIdx.x;
    float* xl = lds;
    float* acc = lds + 32 * F;
    size_t base = (size_t)g * 32 * F;
    for (int i = tid; i < 32 * F; i += blockDim.x) {
        float v = x[base + i];
        xl[i] = v;
        acc[i] = v;          // init with x -> out = x + agg
    }
    if (tid < EPG) {
        es[tid] = src[g * EPG + tid] - g * NPG;
        ed[tid] = dst[g * EPG + tid] - g * NPG;
    }
    __syncthreads();
    if (tid < F) {
        for (int e = 0; e < EPG; ++e)
            acc[ed[e] * F + tid] += xl[es[e] * F + tid];
    }
    __syncthreads();
    for (int i = tid; i < 32 * F; i += blockDim.x)
        out[base + i] = acc[i];
}

// ---------------------------------------------------------------------------
// Global max pool: p[g,f] = max over 32 nodes. Block per graph, 128 threads.
// ---------------------------------------------------------------------------
__global__ void pool_max(const float* __restrict__ h, float* __restrict__ p)
{
    int g = blockIdx.x;
    int f = threadIdx.x;   // 0..127
    float m = -INFINITY;
    size_t base = (size_t)g * NPG * 128 + f;
    #pragma unroll
    for (int n = 0; n < NPG; ++n)
        m = fmaxf(m, h[base + (size_t)n * 128]);
    p[(size_t)g * 128 + f] = m;
}

// ---------------------------------------------------------------------------
// Concat: z[i, :F] = a[i], z[i, F:2F] = b[i]
// ---------------------------------------------------------------------------
__global__ void concat2(const float* __restrict__ a, const float* __restrict__ b,
                        float* __restrict__ z, int M, int F)
{
    size_t idx = (size_t)blockIdx.x * blockDim.x + threadIdx.x;
    if (idx >= (size_t)M * 2 * F) return;
    int i = (int)(idx / (2 * F));
    int j = (int)(idx % (2 * F));
    z[idx] = (j < F) ? a[(size_t)i * F + j] : b[(size_t)i * F + (j - F)];
}

// ---------------------------------------------------------------------------
// Final layer: y[i] = z[i,:] . w + b  (K = 64, N = 1)
// ---------------------------------------------------------------------------
__global__ void final_dot(const float* __restrict__ z, const float* __restrict__ w,
                          const float* __restrict__ b, float* __restrict__ y,
                          int M, int K)
{
    int i = blockIdx.x * blockDim.x + threadIdx.x;
    if (i >= M) return;
    float s = 0.f;
    for (int k = 0; k < K; ++k) s += z[(size_t)i * K + k] * w[k];
    y[i] = s + b[0];
}

// ---------------------------------------------------------------------------
// Host-side driver.
// Workspace budget (~144 MB):
//   big  : NNODE*128 floats (134 MB) — node features, processed IN-PLACE.
//          After pool_max it's dead; cell/head buffers are sub-allocated in it.
//   aux  : NNODE*9 floats (9.4 MB) — GIN1 input, then pbuf.
//   stats: 2*516 floats.
// ---------------------------------------------------------------------------
static inline dim3 gemm_grid(int M, int N) {
    return dim3((M + TILE - 1) / TILE, (N + TILE - 1) / TILE);
}

extern "C" void kernel_launch(void* const* d_in, const int* in_sizes, int n_in,
                              void* d_out, int out_size, void* d_ws, size_t ws_size,
                              hipStream_t stream)
{
    const float* cell   = (const float*)d_in[0];
    const float* drug_x = (const float*)d_in[1];
    const int*   eidx   = (const int*)d_in[2];
    // d_in[3] = drug_batch (unused; structure is implicit)
    const float* ce1w = (const float*)d_in[4];  const float* ce1b = (const float*)d_in[5];
    const float* ce2w = (const float*)d_in[6];  const float* ce2b = (const float*)d_in[7];
    const float* ce3w = (const float*)d_in[8];  const float* ce3b = (const float*)d_in[9];
    const float* g11w = (const float*)d_in[10]; const float* g11b = (const float*)d_in[11];
    const float* g12w = (const float*)d_in[12]; const float* g12b = (const float*)d_in[13];
    const float* g21w = (const float*)d_in[14]; const float* g21b = (const float*)d_in[15];
    const float* g22w = (const float*)d_in[16]; const float* g22b = (const float*)d_in[17];
    const float* d1w  = (const float*)d_in[18]; const float* d1b  = (const float*)d_in[19];
    const float* d2w  = (const float*)d_in[20]; const float* d2b  = (const float*)d_in[21];
    const float* f1w  = (const float*)d_in[22]; const float* f1b  = (const float*)d_in[23];
    const float* f2w  = (const float*)d_in[24]; const float* f2b  = (const float*)d_in[25];
    const float* f3w  = (const float*)d_in[26]; const float* f3b  = (const float*)d_in[27];

    const int* src = eidx;
    const int* dst = eidx + NEDGE;

    float* out = (float*)d_out;

    // ---- workspace layout (~144 MB peak) ----
    float* ws   = (float*)d_ws;
    float* big  = ws;                                   // NNODE*128 = 33,554,432 floats
    float* aux  = ws + (size_t)NNODE * 128;             // NNODE*9   =  2,359,296 floats
    float* stats = aux + (size_t)NNODE * 9;             // 1032 floats
    float* sums  = stats;
    float* sumsq = stats + 516;

    // cell/head buffers live inside `big` (only used after pool_max frees it)
    float* c1    = big;                                  // 8192*516 = 4,227,072
    float* c2    = c1 + (size_t)BGRAPH * 516;            // 8192*256 = 2,097,152
    float* c3    = c2 + (size_t)BGRAPH * 256;            // 8192*128 = 1,048,576
    float* dbuf  = c3 + (size_t)BGRAPH * 128;
    float* d2buf = dbuf + (size_t)BGRAPH * 128;
    float* zbuf  = d2buf + (size_t)BGRAPH * 128;         // 8192*256
    float* f1o   = zbuf + (size_t)BGRAPH * 256;
    float* f2o   = f1o + (size_t)BGRAPH * 128;           // 8192*64
    float* pbuf  = aux;                                  // 8192*128 fits in aux

    auto run_bn = [&](float* x, int M, int C, int prerelu, int act) {
        zero_buf<<<(2 * 516 + 255) / 256, 256, 0, stream>>>(stats, 2 * 516);
        dim3 sg((C + 63) / 64, 128);
        col_stats<<<sg, 64, 0, stream>>>(x, M, C, sums, sumsq, prerelu);
        size_t total = (size_t)M * C;
        bn_norm<<<(int)((total + 255) / 256), 256, 0, stream>>>(x, x, M, C, sums, sumsq, prerelu, act);
    };

    // ================= GIN branch first (uses `big` exclusively) =============
    // GIN conv 1
    gin_agg<<<BGRAPH, 128, 2 * 32 * 9 * sizeof(float), stream>>>(drug_x, src, dst, aux, 9);
    gemm_n128<<<NNODE / TILE, 256, 0, stream>>>(aux, g11w, g11b, big, NNODE, 9, 0);
    run_bn(big, NNODE, 128, 0, 1);                        // relu(bn(.))
    gemm_n128<<<NNODE / TILE, 256, 0, stream>>>(big, g12w, g12b, big, NNODE, 128, 0);  // in-place
    run_bn(big, NNODE, 128, 1, 0);                        // bn(relu(.)) -> h1

    // GIN conv 2
    gin_agg<<<BGRAPH, 128, 2 * 32 * 128 * sizeof(float), stream>>>(big, src, dst, big, 128); // in-place
    gemm_n128<<<NNODE / TILE, 256, 0, stream>>>(big, g21w, g21b, big, NNODE, 128, 0);
    run_bn(big, NNODE, 128, 0, 1);
    gemm_n128<<<NNODE / TILE, 256, 0, stream>>>(big, g22w, g22b, big, NNODE, 128, 0);
    run_bn(big, NNODE, 128, 1, 0);                        // h2

    // pool -> pbuf (in aux); `big` is now free for the small buffers
    pool_max<<<BGRAPH, 128, 0, stream>>>(big, pbuf);

    // ================= cell branch ===========================================
    gemm_bias_act<<<gemm_grid(BGRAPH, 516), 256, 0, stream>>>(cell, ce1w, ce1b, c1, BGRAPH, CELLD, 516, 0);
    run_bn(c1, BGRAPH, 516, 0, 1);
    gemm_bias_act<<<gemm_grid(BGRAPH, 256), 256, 0, stream>>>(c1, ce2w, ce2b, c2, BGRAPH, 516, 256, 0);
    run_bn(c2, BGRAPH, 256, 0, 1);
    gemm_bias_act<<<gemm_grid(BGRAPH, 128), 256, 0, stream>>>(c2, ce3w, ce3b, c3, BGRAPH, 256, 128, 0);
    run_bn(c3, BGRAPH, 128, 0, 1);

    // ================= d branch ==============================================
    gemm_n128<<<BGRAPH / TILE, 256, 0, stream>>>(pbuf, d1w, d1b, dbuf, BGRAPH, 128, 0);
    run_bn(dbuf, BGRAPH, 128, 0, 1);
    gemm_n128<<<BGRAPH / TILE, 256, 0, stream>>>(dbuf, d2w, d2b, d2buf, BGRAPH, 128, 1); // fused relu

    // ================= head ==================================================
    {
        size_t total = (size_t)BGRAPH * 256;
        concat2<<<(int)((total + 255) / 256), 256, 0, stream>>>(c3, d2buf, zbuf, BGRAPH, 128);
    }
    gemm_n128<<<BGRAPH / TILE, 256, 0, stream>>>(zbuf, f1w, f1b, f1o, BGRAPH, 256, 0);
    run_bn(f1o, BGRAPH, 128, 0, 2);                       // elu(bn(.))
    gemm_bias_act<<<gemm_grid(BGRAPH, 64), 256, 0, stream>>>(f1o, f2w, f2b, f2o, BGRAPH, 128, 64, 0);
    run_bn(f2o, BGRAPH, 64, 0, 2);
    final_dot<<<(BGRAPH + 255) / 256, 256, 0, stream>>>(f2o, f3w, f3b, out, BGRAPH, 64);
}

// Round 3
// 1658.890 us; speedup vs baseline: 2.4789x; 2.4789x over previous
//
#include <hip/hip_runtime.h>
#include <hip/hip_bf16.h>
#include <math.h>

// Problem constants (from reference)
#define BGRAPH 8192
#define NPG 32
#define EPG 64
#define NNODE (BGRAPH * NPG)   // 262144
#define NEDGE (BGRAPH * EPG)   // 524288
#define CELLD 908
#define BN_EPS 1e-5f

#define TILE 64
#define TKK 16

// in_mode: 0=raw, 1=relu((x-m)*iv)  [relu(bn(u))], 2=elu((x-m)*iv) [elu(bn(u))],
//          3=(relu(x)-m)*iv         [bn(relu(u))]
__device__ __forceinline__ float apply_in(float v, int mode, float mn, float iv)
{
    if (mode == 1)      { v = (v - mn) * iv; v = fmaxf(v, 0.f); }
    else if (mode == 2) { v = (v - mn) * iv; v = (v > 0.f) ? v : expm1f(v); }
    else if (mode == 3) { v = fmaxf(v, 0.f); v = (v - mn) * iv; }
    return v;
}

__global__ void zero_buf(float* __restrict__ p, int n)
{
    int i = blockIdx.x * blockDim.x + threadIdx.x;
    if (i < n) p[i] = 0.f;
}

// ---------------------------------------------------------------------------
// Generic fused GEMM: C = f_in(A) @ W + bias. Writes u (or relu(u) if out_act).
// Optionally accumulates column stats of u (stats_mode=1) or relu(u) (=2)
// into out_stats [sums(N) | sumsq(N)]. 64x64 tile, 256 thr, 4x4/thread.
// A and C must not alias (different buffers in all uses).
// ---------------------------------------------------------------------------
__launch_bounds__(256)
__global__ void gemm_fused(const float* __restrict__ A, const float* __restrict__ W,
                           const float* __restrict__ bias, float* __restrict__ C,
                           int M, int K, int N,
                           const float* __restrict__ in_stats, float inv_sM, int in_mode,
                           float* __restrict__ out_stats, int stats_mode, int out_act)
{
    __shared__ float As[TKK][TILE + 4];
    __shared__ float Ws[TKK][TILE + 4];
    __shared__ float pmean[520], pinv[520];   // K <= 516 whenever in_mode != 0
    __shared__ float part_s[16 * 64], part_q[16 * 64];
    int tid = threadIdx.x;
    int tx = tid & 15, ty = tid >> 4;
    int m0 = blockIdx.x * TILE, n0 = blockIdx.y * TILE;

    if (in_mode) {
        for (int k = tid; k < K; k += 256) {
            float s = in_stats[k], ss = in_stats[K + k];
            float mn = s * inv_sM;
            float vr = ss * inv_sM - mn * mn;
            pmean[k] = mn;
            pinv[k]  = rsqrtf(vr + BN_EPS);
        }
    }
    __syncthreads();

    float acc[4][4] = {};
    for (int k0 = 0; k0 < K; k0 += TKK) {
        for (int i = tid; i < TILE * TKK; i += 256) {
            int mm = i >> 4, kk = i & 15;
            int gm = m0 + mm, gk = k0 + kk;
            float v = 0.f;
            if (gm < M && gk < K) {
                v = A[(size_t)gm * K + gk];
                if (in_mode) v = apply_in(v, in_mode, pmean[gk], pinv[gk]);
            }
            As[kk][mm] = v;
        }
        for (int i = tid; i < TKK * TILE; i += 256) {
            int kk = i >> 6, nn = i & 63;
            int gk = k0 + kk, gn = n0 + nn;
            Ws[kk][nn] = (gk < K && gn < N) ? W[(size_t)gk * N + gn] : 0.f;
        }
        __syncthreads();
        #pragma unroll
        for (int kk = 0; kk < TKK; ++kk) {
            float a[4], b[4];
            #pragma unroll
            for (int i = 0; i < 4; ++i) a[i] = As[kk][ty * 4 + i];
            #pragma unroll
            for (int j = 0; j < 4; ++j) b[j] = Ws[kk][tx * 4 + j];
            #pragma unroll
            for (int i = 0; i < 4; ++i)
                #pragma unroll
                for (int j = 0; j < 4; ++j)
                    acc[i][j] += a[i] * b[j];
        }
        __syncthreads();
    }

    float bj[4];
    #pragma unroll
    for (int j = 0; j < 4; ++j) {
        int gn = n0 + tx * 4 + j;
        bj[j] = (gn < N) ? bias[gn] : 0.f;
    }
    float ls[4] = {0, 0, 0, 0}, lq[4] = {0, 0, 0, 0};
    #pragma unroll
    for (int i = 0; i < 4; ++i) {
        int gm = m0 + ty * 4 + i;
        if (gm >= M) continue;
        #pragma unroll
        for (int j = 0; j < 4; ++j) {
            int gn = n0 + tx * 4 + j;
            if (gn >= N) continue;
            float u = acc[i][j] + bj[j];
            float wv = (out_act == 1) ? fmaxf(u, 0.f) : u;
            C[(size_t)gm * N + gn] = wv;
            if (stats_mode) {
                float v = (stats_mode == 2) ? fmaxf(u, 0.f) : u;
                ls[j] += v; lq[j] += v * v;
            }
        }
    }
    if (stats_mode) {
        #pragma unroll
        for (int j = 0; j < 4; ++j) {
            part_s[ty * 64 + tx * 4 + j] = ls[j];
            part_q[ty * 64 + tx * 4 + j] = lq[j];
        }
        __syncthreads();
        if (tid < 64) {
            int gn = n0 + tid;
            if (gn < N) {
                float s = 0.f, q = 0.f;
                #pragma unroll
                for (int t = 0; t < 16; ++t) { s += part_s[t * 64 + tid]; q += part_q[t * 64 + tid]; }
                unsafeAtomicAdd(&out_stats[gn], s);
                unsafeAtomicAdd(&out_stats[N + gn], q);
            }
        }
    }
}

// ---------------------------------------------------------------------------
// N=128 fused GEMM, full output rows per block -> SAFE IN-PLACE (A may == C).
// 64 rows x 128 cols per block, 256 threads, 8x4 per thread. K <= 256.
// ---------------------------------------------------------------------------
__launch_bounds__(256)
__global__ void gemm_fused_n128(const float* __restrict__ A, const float* __restrict__ W,
                                const float* __restrict__ bias, float* __restrict__ C,
                                int M, int K,
                                const float* __restrict__ in_stats, float inv_sM, int in_mode,
                                float* __restrict__ out_stats, int stats_mode, int out_act)
{
    __shared__ float As[TKK][TILE + 4];
    __shared__ float Ws[TKK][128 + 4];
    __shared__ float pmean[256], pinv[256];
    __shared__ float part_s[8 * 128], part_q[8 * 128];
    int tid = threadIdx.x;
    int tx = tid & 31, ty = tid >> 5;
    int m0 = blockIdx.x * TILE;

    if (in_mode) {
        for (int k = tid; k < K; k += 256) {
            float s = in_stats[k], ss = in_stats[K + k];
            float mn = s * inv_sM;
            float vr = ss * inv_sM - mn * mn;
            pmean[k] = mn;
            pinv[k]  = rsqrtf(vr + BN_EPS);
        }
    }
    __syncthreads();

    float acc[8][4] = {};
    for (int k0 = 0; k0 < K; k0 += TKK) {
        for (int i = tid; i < TILE * TKK; i += 256) {
            int mm = i >> 4, kk = i & 15;
            int gm = m0 + mm, gk = k0 + kk;
            float v = 0.f;
            if (gm < M && gk < K) {
                v = A[(size_t)gm * K + gk];
                if (in_mode) v = apply_in(v, in_mode, pmean[gk], pinv[gk]);
            }
            As[kk][mm] = v;
        }
        for (int i = tid; i < TKK * 128; i += 256) {
            int kk = i >> 7, nn = i & 127;
            int gk = k0 + kk;
            Ws[kk][nn] = (gk < K) ? W[(size_t)gk * 128 + nn] : 0.f;
        }
        __syncthreads();
        #pragma unroll
        for (int kk = 0; kk < TKK; ++kk) {
            float a[8], b[4];
            #pragma unroll
            for (int i = 0; i < 8; ++i) a[i] = As[kk][ty * 8 + i];
            #pragma unroll
            for (int j = 0; j < 4; ++j) b[j] = Ws[kk][tx * 4 + j];
            #pragma unroll
            for (int i = 0; i < 8; ++i)
                #pragma unroll
                for (int j = 0; j < 4; ++j)
                    acc[i][j] += a[i] * b[j];
        }
        __syncthreads();
    }

    float bj[4];
    #pragma unroll
    for (int j = 0; j < 4; ++j) bj[j] = bias[tx * 4 + j];
    float ls[4] = {0, 0, 0, 0}, lq[4] = {0, 0, 0, 0};
    #pragma unroll
    for (int i = 0; i < 8; ++i) {
        int gm = m0 + ty * 8 + i;
        if (gm >= M) continue;
        #pragma unroll
        for (int j = 0; j < 4; ++j) {
            float u = acc[i][j] + bj[j];
            float wv = (out_act == 1) ? fmaxf(u, 0.f) : u;
            C[(size_t)gm * 128 + tx * 4 + j] = wv;
            if (stats_mode) {
                float v = (stats_mode == 2) ? fmaxf(u, 0.f) : u;
                ls[j] += v; lq[j] += v * v;
            }
        }
    }
    if (stats_mode) {
        #pragma unroll
        for (int j = 0; j < 4; ++j) {
            part_s[ty * 128 + tx * 4 + j] = ls[j];
            part_q[ty * 128 + tx * 4 + j] = lq[j];
        }
        __syncthreads();
        if (tid < 128) {
            float s = 0.f, q = 0.f;
            #pragma unroll
            for (int t = 0; t < 8; ++t) { s += part_s[t * 128 + tid]; q += part_q[t * 128 + tid]; }
            unsafeAtomicAdd(&out_stats[tid], s);
            unsafeAtomicAdd(&out_stats[128 + tid], q);
        }
    }
}

// ---------------------------------------------------------------------------
// GIN aggregation, one graph per block: out = f(x) + segment_sum(f(x)[src], dst)
// where f is the in_mode transform. Block-local via LDS -> SAFE IN-PLACE.
// ---------------------------------------------------------------------------
__global__ void gin_agg(const float* __restrict__ x, const int* __restrict__ src,
                        const int* __restrict__ dst, float* __restrict__ out, int F,
                        const float* __restrict__ in_stats, float inv_sM, int in_mode)
{
    extern __shared__ float lds[];
    __shared__ int es[EPG], ed[EPG];
    int g = blockIdx.x;
    int tid = threadIdx.x;
    float* xl  = lds;
    float* acc = lds + 32 * F;
    float* pm  = acc + 32 * F;
    float* pi  = pm + F;
    if (in_mode && tid < F) {
        float s = in_stats[tid], ss = in_stats[F + tid];
        float mn = s * inv_sM;
        float vr = ss * inv_sM - mn * mn;
        pm[tid] = mn;
        pi[tid] = rsqrtf(vr + BN_EPS);
    }
    if (tid < EPG) {
        es[tid] = src[g * EPG + tid] - g * NPG;
        ed[tid] = dst[g * EPG + tid] - g * NPG;
    }
    __syncthreads();
    size_t base = (size_t)g * 32 * F;
    for (int i = tid; i < 32 * F; i += blockDim.x) {
        float v = x[base + i];
        if (in_mode) {
            int col = i % F;
            v = apply_in(v, in_mode, pm[col], pi[col]);
        }
        xl[i] = v;
        acc[i] = v;          // init with x -> out = x + agg
    }
    __syncthreads();
    if (tid < F) {
        for (int e = 0; e < EPG; ++e)
            acc[ed[e] * F + tid] += xl[es[e] * F + tid];
    }
    __syncthreads();
    for (int i = tid; i < 32 * F; i += blockDim.x)
        out[base + i] = acc[i];
}

// ---------------------------------------------------------------------------
// Pool: p[g,f] = bn(max_n relu(u[g*32+n, f])). Norm is monotone (iv>0) so it
// commutes with max. Stats are over relu(u) across all NNODE rows.
// ---------------------------------------------------------------------------
__global__ void pool_max(const float* __restrict__ h, float* __restrict__ p,
                         const float* __restrict__ stats, float inv_sM)
{
    int g = blockIdx.x;
    int f = threadIdx.x;   // 0..127
    float s = stats[f], ss = stats[128 + f];
    float mn = s * inv_sM;
    float vr = ss * inv_sM - mn * mn;
    float iv = rsqrtf(vr + BN_EPS);
    float m = -INFINITY;
    size_t base = (size_t)g * NPG * 128 + f;
    #pragma unroll
    for (int n = 0; n < NPG; ++n)
        m = fmaxf(m, fmaxf(h[base + (size_t)n * 128], 0.f));
    p[(size_t)g * 128 + f] = (m - mn) * iv;
}

// ---------------------------------------------------------------------------
// Concat: z[i,:128] = relu(bn(c3u[i])), z[i,128:] = d2[i]
// ---------------------------------------------------------------------------
__global__ void concat2(const float* __restrict__ c3u, const float* __restrict__ d2,
                        float* __restrict__ z, const float* __restrict__ stats,
                        float inv_sM)
{
    size_t idx = (size_t)blockIdx.x * blockDim.x + threadIdx.x;
    if (idx >= (size_t)BGRAPH * 256) return;
    int i = (int)(idx >> 8);
    int j = (int)(idx & 255);
    float v;
    if (j < 128) {
        float s = stats[j], ss = stats[128 + j];
        float mn = s * inv_sM;
        float vr = ss * inv_sM - mn * mn;
        float iv = rsqrtf(vr + BN_EPS);
        v = fmaxf((c3u[(size_t)i * 128 + j] - mn) * iv, 0.f);
    } else {
        v = d2[(size_t)i * 128 + (j - 128)];
    }
    z[idx] = v;
}

// ---------------------------------------------------------------------------
// Final: y[i] = elu(bn(u11[i,:])) . w + b   (K = 64)
// ---------------------------------------------------------------------------
__global__ void final_dot(const float* __restrict__ u, const float* __restrict__ w,
                          const float* __restrict__ b, float* __restrict__ y,
                          const float* __restrict__ stats, float inv_sM)
{
    __shared__ float pm[64], pi[64], sw[64];
    int tid = threadIdx.x;
    if (tid < 64) {
        float s = stats[tid], ss = stats[64 + tid];
        float mn = s * inv_sM;
        float vr = ss * inv_sM - mn * mn;
        pm[tid] = mn;
        pi[tid] = rsqrtf(vr + BN_EPS);
        sw[tid] = w[tid];
    }
    __syncthreads();
    int i = blockIdx.x * blockDim.x + tid;
    if (i >= BGRAPH) return;
    float acc = 0.f;
    #pragma unroll
    for (int k = 0; k < 64; ++k) {
        float v = (u[(size_t)i * 64 + k] - pm[k]) * pi[k];
        v = (v > 0.f) ? v : expm1f(v);
        acc += v * sw[k];
    }
    y[i] = acc + b[0];
}

// ---------------------------------------------------------------------------
// Host driver. 17 launches, ~144 MB workspace.
// ---------------------------------------------------------------------------
extern "C" void kernel_launch(void* const* d_in, const int* in_sizes, int n_in,
                              void* d_out, int out_size, void* d_ws, size_t ws_size,
                              hipStream_t stream)
{
    const float* cell   = (const float*)d_in[0];
    const float* drug_x = (const float*)d_in[1];
    const int*   eidx   = (const int*)d_in[2];
    const float* ce1w = (const float*)d_in[4];  const float* ce1b = (const float*)d_in[5];
    const float* ce2w = (const float*)d_in[6];  const float* ce2b = (const float*)d_in[7];
    const float* ce3w = (const float*)d_in[8];  const float* ce3b = (const float*)d_in[9];
    const float* g11w = (const float*)d_in[10]; const float* g11b = (const float*)d_in[11];
    const float* g12w = (const float*)d_in[12]; const float* g12b = (const float*)d_in[13];
    const float* g21w = (const float*)d_in[14]; const float* g21b = (const float*)d_in[15];
    const float* g22w = (const float*)d_in[16]; const float* g22b = (const float*)d_in[17];
    const float* d1w  = (const float*)d_in[18]; const float* d1b  = (const float*)d_in[19];
    const float* d2w  = (const float*)d_in[20]; const float* d2b  = (const float*)d_in[21];
    const float* f1w  = (const float*)d_in[22]; const float* f1b  = (const float*)d_in[23];
    const float* f2w  = (const float*)d_in[24]; const float* f2b  = (const float*)d_in[25];
    const float* f3w  = (const float*)d_in[26]; const float* f3b  = (const float*)d_in[27];

    const int* src = eidx;
    const int* dst = eidx + NEDGE;
    float* out = (float*)d_out;

    const float INV_N = 1.f / (float)NNODE;
    const float INV_B = 1.f / (float)BGRAPH;

    // ---- workspace layout ----
    float* ws   = (float*)d_ws;
    float* big  = ws;                                   // NNODE*128
    float* aux  = ws + (size_t)NNODE * 128;             // NNODE*9 (>= BGRAPH*128)
    float* sb   = aux + (size_t)NNODE * 9;              // 10 * 1032 stats floats
    auto ST = [&](int i) { return sb + (size_t)i * 1032; };
    float* st_u1    = ST(0);   // GIN g1_1 pre-act (stats of u)
    float* st_u2rel = ST(1);   // GIN g1_2: stats of relu(u)
    float* st_u3    = ST(2);   // GIN g2_1
    float* st_u4rel = ST(3);   // GIN g2_2: stats of relu(u)
    float* st_c1    = ST(4);
    float* st_c2    = ST(5);
    float* st_c3    = ST(6);
    float* st_d1    = ST(7);
    float* st_f1    = ST(8);
    float* st_f2    = ST(9);

    // small buffers live inside `big` after pool_max frees it
    float* c1    = big;
    float* c2    = c1 + (size_t)BGRAPH * 516;
    float* c3u   = c2 + (size_t)BGRAPH * 256;
    float* dbuf  = c3u + (size_t)BGRAPH * 128;
    float* d2buf = dbuf + (size_t)BGRAPH * 128;
    float* zbuf  = d2buf + (size_t)BGRAPH * 128;
    float* f1o   = zbuf + (size_t)BGRAPH * 256;
    float* f2o   = f1o + (size_t)BGRAPH * 128;
    float* pbuf  = aux;   // reused after gin1's input is consumed

    zero_buf<<<(10 * 1032 + 255) / 256, 256, 0, stream>>>(sb, 10 * 1032);

    // ================= GIN branch (in-place in `big`) ========================
    gin_agg<<<BGRAPH, 128, (2 * 32 * 9 + 2 * 9) * sizeof(float), stream>>>(
        drug_x, src, dst, aux, 9, nullptr, 0.f, 0);
    gemm_fused_n128<<<NNODE / TILE, 256, 0, stream>>>(
        aux, g11w, g11b, big, NNODE, 9, nullptr, 0.f, 0, st_u1, 1, 0);
    gemm_fused_n128<<<NNODE / TILE, 256, 0, stream>>>(
        big, g12w, g12b, big, NNODE, 128, st_u1, INV_N, 1, st_u2rel, 2, 0);
    gin_agg<<<BGRAPH, 128, (2 * 32 * 128 + 2 * 128) * sizeof(float), stream>>>(
        big, src, dst, big, 128, st_u2rel, INV_N, 3);
    gemm_fused_n128<<<NNODE / TILE, 256, 0, stream>>>(
        big, g21w, g21b, big, NNODE, 128, nullptr, 0.f, 0, st_u3, 1, 0);
    gemm_fused_n128<<<NNODE / TILE, 256, 0, stream>>>(
        big, g22w, g22b, big, NNODE, 128, st_u3, INV_N, 1, st_u4rel, 2, 0);
    pool_max<<<BGRAPH, 128, 0, stream>>>(big, pbuf, st_u4rel, INV_N);

    // ================= cell branch ===========================================
    gemm_fused<<<dim3(BGRAPH / TILE, (516 + TILE - 1) / TILE), 256, 0, stream>>>(
        cell, ce1w, ce1b, c1, BGRAPH, CELLD, 516, nullptr, 0.f, 0, st_c1, 1, 0);
    gemm_fused<<<dim3(BGRAPH / TILE, 256 / TILE), 256, 0, stream>>>(
        c1, ce2w, ce2b, c2, BGRAPH, 516, 256, st_c1, INV_B, 1, st_c2, 1, 0);
    gemm_fused_n128<<<BGRAPH / TILE, 256, 0, stream>>>(
        c2, ce3w, ce3b, c3u, BGRAPH, 256, st_c2, INV_B, 1, st_c3, 1, 0);

    // ================= d branch ==============================================
    gemm_fused_n128<<<BGRAPH / TILE, 256, 0, stream>>>(
        pbuf, d1w, d1b, dbuf, BGRAPH, 128, nullptr, 0.f, 0, st_d1, 1, 0);
    gemm_fused_n128<<<BGRAPH / TILE, 256, 0, stream>>>(
        dbuf, d2w, d2b, d2buf, BGRAPH, 128, st_d1, INV_B, 1, nullptr, 0, 1);

    // ================= head ==================================================
    concat2<<<(BGRAPH * 256 + 255) / 256, 256, 0, stream>>>(
        c3u, d2buf, zbuf, st_c3, INV_B);
    gemm_fused_n128<<<BGRAPH / TILE, 256, 0, stream>>>(
        zbuf, f1w, f1b, f1o, BGRAPH, 256, nullptr, 0.f, 0, st_f1, 1, 0);
    gemm_fused<<<dim3(BGRAPH / TILE, 1), 256, 0, stream>>>(
        f1o, f2w, f2b, f2o, BGRAPH, 128, 64, st_f1, INV_B, 2, st_f2, 1, 0);
    final_dot<<<BGRAPH / 256, 256, 0, stream>>>(f2o, f3w, f3b, out, st_f2, INV_B);
}

// Round 4
// 1079.980 us; speedup vs baseline: 3.8077x; 1.5360x over previous
//
#include <hip/hip_runtime.h>
#include <hip/hip_bf16.h>
#include <math.h>

// Problem constants (from reference)
#define BGRAPH 8192
#define NPG 32
#define EPG 64
#define NNODE (BGRAPH * NPG)   // 262144
#define NEDGE (BGRAPH * EPG)   // 524288
#define CELLD 908
#define BN_EPS 1e-5f

typedef __attribute__((ext_vector_type(8))) short bf16x8;   // 8 bf16 = 4 VGPRs
typedef __attribute__((ext_vector_type(4))) float f32x4;
typedef __attribute__((ext_vector_type(4))) unsigned short us4;

__device__ __forceinline__ unsigned short f2bf(float f)
{
    unsigned int u = __float_as_uint(f);
    u = (u + 0x7FFFu + ((u >> 16) & 1u)) >> 16;   // RNE
    return (unsigned short)u;
}

// in_mode: 0=raw, 1=relu((x-m)*iv), 2=elu((x-m)*iv), 3=(relu(x)-m)*iv
__device__ __forceinline__ float apply_in(float v, int mode, float mn, float iv)
{
    if (mode == 1)      { v = (v - mn) * iv; v = fmaxf(v, 0.f); }
    else if (mode == 2) { v = (v - mn) * iv; v = (v > 0.f) ? v : expm1f(v); }
    else if (mode == 3) { v = fmaxf(v, 0.f); v = (v - mn) * iv; }
    return v;
}

__global__ void zero_buf(float* __restrict__ p, int n)
{
    int i = blockIdx.x * blockDim.x + threadIdx.x;
    if (i < n) p[i] = 0.f;
}

// ---------------------------------------------------------------------------
// Fused weight transpose+convert: wt[n*K+k] = bf16(w[k*N+n]) for 11 layers.
// ---------------------------------------------------------------------------
struct TSeg { const float* w; unsigned short* wt; int K; int N; int off; };
struct TArgs { TSeg s[11]; int total; };

__global__ void transpose_w(TArgs a)
{
    int i = blockIdx.x * blockDim.x + threadIdx.x;
    if (i >= a.total) return;
    int j = 0;
    while (j < 10 && i >= a.s[j + 1].off) ++j;
    int idx = i - a.s[j].off;
    int K = a.s[j].K, N = a.s[j].N;
    int n = idx / K, k = idx - n * K;
    a.s[j].wt[idx] = f2bf(a.s[j].w[(size_t)k * N + n]);
}

// ---------------------------------------------------------------------------
// MFMA GEMM: C[M,N] = f_in(A[M,K]) @ W + bias, A fp32, W pre-transposed bf16
// [N][K]. Tile 128 x NT, K-chunk 64, 256 threads = 4 waves (32 rows each).
// Optional column stats of u / relu(u) -> out_stats. In-place safe (A==C ok:
// each block reads only its own 128 rows, all reads precede epilogue writes).
// M must be a multiple of 128.
// ---------------------------------------------------------------------------
#define KC 64
#define LSTR 72   // LDS row stride in ushorts (64 + 8 pad -> 2-way conflicts only)

template<int NT>
__launch_bounds__(256)
__global__ void gemm_mfma(const float* __restrict__ A, const unsigned short* __restrict__ Wt,
                          const float* __restrict__ bias, float* __restrict__ C,
                          int M, int K, int N,
                          const float* __restrict__ in_stats, float inv_sM, int in_mode,
                          float* __restrict__ out_stats, int stats_mode, int out_act)
{
    __shared__ unsigned short As_l[128 * LSTR];
    __shared__ unsigned short Ws_l[NT * LSTR];
    __shared__ float pm[520], pv[520];          // in_mode only used with K<=516
    __shared__ float red[4][2][NT];

    constexpr int NSUB = NT / 16;
    int tid  = threadIdx.x;
    int wave = tid >> 6;
    int lane = tid & 63;
    int quad = lane >> 4;
    int l16  = lane & 15;
    int m0 = blockIdx.x * 128;
    int n0 = blockIdx.y * NT;

    if (in_mode) {
        for (int k = tid; k < K; k += 256) {
            float s = in_stats[k], ss = in_stats[K + k];
            float mn = s * inv_sM;
            float vr = ss * inv_sM - mn * mn;
            pm[k] = mn;
            pv[k] = rsqrtf(vr + BN_EPS);
        }
        __syncthreads();
    }

    f32x4 acc[2][NSUB];
    #pragma unroll
    for (int i = 0; i < 2; ++i)
        #pragma unroll
        for (int j = 0; j < NSUB; ++j)
            acc[i][j] = (f32x4){0.f, 0.f, 0.f, 0.f};

    const bool vec_ok = ((K & 3) == 0);

    for (int k0 = 0; k0 < K; k0 += KC) {
        // ---- stage A: 128 rows x 64 k, fp32 -> (BN transform) -> bf16 ----
        for (int i = tid; i < 128 * 16; i += 256) {
            int row = i >> 4, f4 = i & 15;
            int k = k0 + f4 * 4;
            float v0 = 0.f, v1 = 0.f, v2 = 0.f, v3 = 0.f;
            if (k < K) {
                const float* ap = A + (size_t)(m0 + row) * K + k;
                if (vec_ok) {
                    float4 f = *(const float4*)ap;
                    v0 = f.x; v1 = f.y; v2 = f.z; v3 = f.w;
                } else {
                    v0 = ap[0];
                    if (k + 1 < K) v1 = ap[1];
                    if (k + 2 < K) v2 = ap[2];
                    if (k + 3 < K) v3 = ap[3];
                }
                if (in_mode) {
                    v0 = apply_in(v0, in_mode, pm[k], pv[k]);
                    if (k + 1 < K) v1 = apply_in(v1, in_mode, pm[k + 1], pv[k + 1]);
                    if (k + 2 < K) v2 = apply_in(v2, in_mode, pm[k + 2], pv[k + 2]);
                    if (k + 3 < K) v3 = apply_in(v3, in_mode, pm[k + 3], pv[k + 3]);
                }
            }
            us4 w4 = { f2bf(v0), f2bf(v1), f2bf(v2), f2bf(v3) };
            // padding lanes (k>=K) may hold bf16(0)=0; W padding is 0 anyway
            if (k >= K) w4 = (us4){0, 0, 0, 0};
            *(us4*)&As_l[row * LSTR + f4 * 4] = w4;
        }
        // ---- stage Wt: NT rows x 64 k, already bf16 [N][K] ----
        for (int i = tid; i < NT * 16; i += 256) {
            int nn = i >> 4, kt = i & 15;
            int k = k0 + kt * 4;
            int gn = n0 + nn;
            us4 w4 = (us4){0, 0, 0, 0};
            if (gn < N && k < K) {
                const unsigned short* wp = Wt + (size_t)gn * K + k;
                if (vec_ok) {
                    w4 = *(const us4*)wp;     // K%4==0 -> 8B aligned
                } else {
                    w4.x = wp[0];
                    if (k + 1 < K) w4.y = wp[1];
                    if (k + 2 < K) w4.z = wp[2];
                    if (k + 3 < K) w4.w = wp[3];
                }
            }
            *(us4*)&Ws_l[nn * LSTR + kt * 4] = w4;
        }
        __syncthreads();

        // ---- MFMA: 2 k-steps of 32 ----
        int mbase = wave * 32;
        #pragma unroll
        for (int ks = 0; ks < 2; ++ks) {
            bf16x8 a0 = *(const bf16x8*)(const void*)&As_l[(mbase + l16) * LSTR + ks * 32 + quad * 8];
            bf16x8 a1 = *(const bf16x8*)(const void*)&As_l[(mbase + 16 + l16) * LSTR + ks * 32 + quad * 8];
            #pragma unroll
            for (int nt = 0; nt < NSUB; ++nt) {
                bf16x8 b = *(const bf16x8*)(const void*)&Ws_l[(nt * 16 + l16) * LSTR + ks * 32 + quad * 8];
                acc[0][nt] = __builtin_amdgcn_mfma_f32_16x16x32_bf16(a0, b, acc[0][nt], 0, 0, 0);
                acc[1][nt] = __builtin_amdgcn_mfma_f32_16x16x32_bf16(a1, b, acc[1][nt], 0, 0, 0);
            }
        }
        __syncthreads();
    }

    // ---- epilogue: bias, act, store, column stats ----
    float ls[NSUB], lq[NSUB];
    #pragma unroll
    for (int nt = 0; nt < NSUB; ++nt) { ls[nt] = 0.f; lq[nt] = 0.f; }

    #pragma unroll
    for (int mt = 0; mt < 2; ++mt) {
        int rbase = m0 + wave * 32 + mt * 16 + quad * 4;
        #pragma unroll
        for (int nt = 0; nt < NSUB; ++nt) {
            int col = n0 + nt * 16 + l16;
            if (col < N) {
                float bv = bias[col];
                #pragma unroll
                for (int r = 0; r < 4; ++r) {
                    float u = acc[mt][nt][r] + bv;
                    float wv = out_act ? fmaxf(u, 0.f) : u;
                    C[(size_t)(rbase + r) * N + col] = wv;
                    if (stats_mode) {
                        float v = (stats_mode == 2) ? fmaxf(u, 0.f) : u;
                        ls[nt] += v; lq[nt] += v * v;
                    }
                }
            }
        }
    }

    if (stats_mode) {
        #pragma unroll
        for (int nt = 0; nt < NSUB; ++nt) {
            float s = ls[nt], q = lq[nt];
            s += __shfl_xor(s, 16); q += __shfl_xor(q, 16);
            s += __shfl_xor(s, 32); q += __shfl_xor(q, 32);
            if (quad == 0) { red[wave][0][nt * 16 + l16] = s; red[wave][1][nt * 16 + l16] = q; }
        }
        __syncthreads();
        if (tid < NT) {
            int col = n0 + tid;
            if (col < N) {
                float s = red[0][0][tid] + red[1][0][tid] + red[2][0][tid] + red[3][0][tid];
                float q = red[0][1][tid] + red[1][1][tid] + red[2][1][tid] + red[3][1][tid];
                unsafeAtomicAdd(&out_stats[col], s);
                unsafeAtomicAdd(&out_stats[N + col], q);
            }
        }
    }
}

// ---------------------------------------------------------------------------
// GIN aggregation, one graph per block: out = f(x) + segment_sum(f(x)[src], dst)
// Block-local via LDS -> SAFE IN-PLACE.
// ---------------------------------------------------------------------------
__global__ void gin_agg(const float* __restrict__ x, const int* __restrict__ src,
                        const int* __restrict__ dst, float* __restrict__ out, int F,
                        const float* __restrict__ in_stats, float inv_sM, int in_mode)
{
    extern __shared__ float lds[];
    __shared__ int es[EPG], ed[EPG];
    int g = blockIdx.x;
    int tid = threadIdx.x;
    float* xl  = lds;
    float* acc = lds + 32 * F;
    float* pmv = acc + 32 * F;
    float* piv = pmv + F;
    if (in_mode && tid < F) {
        float s = in_stats[tid], ss = in_stats[F + tid];
        float mn = s * inv_sM;
        float vr = ss * inv_sM - mn * mn;
        pmv[tid] = mn;
        piv[tid] = rsqrtf(vr + BN_EPS);
    }
    if (tid < EPG) {
        es[tid] = src[g * EPG + tid] - g * NPG;
        ed[tid] = dst[g * EPG + tid] - g * NPG;
    }
    __syncthreads();
    size_t base = (size_t)g * 32 * F;
    for (int i = tid; i < 32 * F; i += blockDim.x) {
        float v = x[base + i];
        if (in_mode) {
            int col = i % F;
            v = apply_in(v, in_mode, pmv[col], piv[col]);
        }
        xl[i] = v;
        acc[i] = v;
    }
    __syncthreads();
    if (tid < F) {
        for (int e = 0; e < EPG; ++e)
            acc[ed[e] * F + tid] += xl[es[e] * F + tid];
    }
    __syncthreads();
    for (int i = tid; i < 32 * F; i += blockDim.x)
        out[base + i] = acc[i];
}

// ---------------------------------------------------------------------------
// Pool: p[g,f] = bn(max_n relu(u)); norm monotone -> commutes with max.
// ---------------------------------------------------------------------------
__global__ void pool_max(const float* __restrict__ h, float* __restrict__ p,
                         const float* __restrict__ stats, float inv_sM)
{
    int g = blockIdx.x;
    int f = threadIdx.x;
    float s = stats[f], ss = stats[128 + f];
    float mn = s * inv_sM;
    float vr = ss * inv_sM - mn * mn;
    float iv = rsqrtf(vr + BN_EPS);
    float m = -INFINITY;
    size_t base = (size_t)g * NPG * 128 + f;
    #pragma unroll
    for (int n = 0; n < NPG; ++n)
        m = fmaxf(m, fmaxf(h[base + (size_t)n * 128], 0.f));
    p[(size_t)g * 128 + f] = (m - mn) * iv;
}

// ---------------------------------------------------------------------------
// Concat: z[i,:128] = relu(bn(c3u[i])), z[i,128:] = d2[i]
// ---------------------------------------------------------------------------
__global__ void concat2(const float* __restrict__ c3u, const float* __restrict__ d2,
                        float* __restrict__ z, const float* __restrict__ stats,
                        float inv_sM)
{
    size_t idx = (size_t)blockIdx.x * blockDim.x + threadIdx.x;
    if (idx >= (size_t)BGRAPH * 256) return;
    int i = (int)(idx >> 8);
    int j = (int)(idx & 255);
    float v;
    if (j < 128) {
        float s = stats[j], ss = stats[128 + j];
        float mn = s * inv_sM;
        float vr = ss * inv_sM - mn * mn;
        float iv = rsqrtf(vr + BN_EPS);
        v = fmaxf((c3u[(size_t)i * 128 + j] - mn) * iv, 0.f);
    } else {
        v = d2[(size_t)i * 128 + (j - 128)];
    }
    z[idx] = v;
}

// ---------------------------------------------------------------------------
// Final: y[i] = elu(bn(u[i,:])) . w + b   (K = 64)
// ---------------------------------------------------------------------------
__global__ void final_dot(const float* __restrict__ u, const float* __restrict__ w,
                          const float* __restrict__ b, float* __restrict__ y,
                          const float* __restrict__ stats, float inv_sM)
{
    __shared__ float pmv[64], piv[64], sw[64];
    int tid = threadIdx.x;
    if (tid < 64) {
        float s = stats[tid], ss = stats[64 + tid];
        float mn = s * inv_sM;
        float vr = ss * inv_sM - mn * mn;
        pmv[tid] = mn;
        piv[tid] = rsqrtf(vr + BN_EPS);
        sw[tid] = w[tid];
    }
    __syncthreads();
    int i = blockIdx.x * blockDim.x + tid;
    if (i >= BGRAPH) return;
    float acc = 0.f;
    #pragma unroll
    for (int k = 0; k < 64; ++k) {
        float v = (u[(size_t)i * 64 + k] - pmv[k]) * piv[k];
        v = (v > 0.f) ? v : expm1f(v);
        acc += v * sw[k];
    }
    y[i] = acc + b[0];
}

// ---------------------------------------------------------------------------
// Host driver. ~145 MB workspace.
// ---------------------------------------------------------------------------
extern "C" void kernel_launch(void* const* d_in, const int* in_sizes, int n_in,
                              void* d_out, int out_size, void* d_ws, size_t ws_size,
                              hipStream_t stream)
{
    const float* cell   = (const float*)d_in[0];
    const float* drug_x = (const float*)d_in[1];
    const int*   eidx   = (const int*)d_in[2];
    const float* ce1w = (const float*)d_in[4];  const float* ce1b = (const float*)d_in[5];
    const float* ce2w = (const float*)d_in[6];  const float* ce2b = (const float*)d_in[7];
    const float* ce3w = (const float*)d_in[8];  const float* ce3b = (const float*)d_in[9];
    const float* g11w = (const float*)d_in[10]; const float* g11b = (const float*)d_in[11];
    const float* g12w = (const float*)d_in[12]; const float* g12b = (const float*)d_in[13];
    const float* g21w = (const float*)d_in[14]; const float* g21b = (const float*)d_in[15];
    const float* g22w = (const float*)d_in[16]; const float* g22b = (const float*)d_in[17];
    const float* d1w  = (const float*)d_in[18]; const float* d1b  = (const float*)d_in[19];
    const float* d2w  = (const float*)d_in[20]; const float* d2b  = (const float*)d_in[21];
    const float* f1w  = (const float*)d_in[22]; const float* f1b  = (const float*)d_in[23];
    const float* f2w  = (const float*)d_in[24]; const float* f2b  = (const float*)d_in[25];
    const float* f3w  = (const float*)d_in[26]; const float* f3b  = (const float*)d_in[27];

    const int* src = eidx;
    const int* dst = eidx + NEDGE;
    float* out = (float*)d_out;

    const float INV_N = 1.f / (float)NNODE;
    const float INV_B = 1.f / (float)BGRAPH;

    // ---- workspace layout ----
    float* ws   = (float*)d_ws;
    float* big  = ws;                                   // NNODE*128 floats
    float* aux  = ws + (size_t)NNODE * 128;             // NNODE*9 floats
    float* sb   = aux + (size_t)NNODE * 9;              // 10*1032 stats floats
    unsigned short* wtb = (unsigned short*)(sb + 10 * 1032);
    auto ST = [&](int i) { return sb + (size_t)i * 1032; };
    float* st_u1    = ST(0);
    float* st_u2rel = ST(1);
    float* st_u3    = ST(2);
    float* st_u4rel = ST(3);
    float* st_c1    = ST(4);
    float* st_c2    = ST(5);
    float* st_c3    = ST(6);
    float* st_d1    = ST(7);
    float* st_f1    = ST(8);
    float* st_f2    = ST(9);

    // transposed bf16 weights [N][K]
    struct WDef { const float* w; int K; int N; };
    WDef wd[11] = {
        {ce1w, CELLD, 516}, {ce2w, 516, 256}, {ce3w, 256, 128},
        {g11w, 9, 128}, {g12w, 128, 128}, {g21w, 128, 128}, {g22w, 128, 128},
        {d1w, 128, 128}, {d2w, 128, 128}, {f1w, 256, 128}, {f2w, 128, 64}
    };
    TArgs ta;
    int off = 0;
    unsigned short* wt[11];
    for (int i = 0; i < 11; ++i) {
        wt[i] = wtb + off;
        ta.s[i] = TSeg{ wd[i].w, wt[i], wd[i].K, wd[i].N, off };
        off += wd[i].K * wd[i].N;
    }
    ta.total = off;
    unsigned short* wt_ce1 = wt[0];  unsigned short* wt_ce2 = wt[1];
    unsigned short* wt_ce3 = wt[2];  unsigned short* wt_g11 = wt[3];
    unsigned short* wt_g12 = wt[4];  unsigned short* wt_g21 = wt[5];
    unsigned short* wt_g22 = wt[6];  unsigned short* wt_d1  = wt[7];
    unsigned short* wt_d2  = wt[8];  unsigned short* wt_f1  = wt[9];
    unsigned short* wt_f2  = wt[10];

    // small buffers live inside `big` after pool_max frees it
    float* c1    = big;
    float* c2    = c1 + (size_t)BGRAPH * 516;
    float* c3u   = c2 + (size_t)BGRAPH * 256;
    float* dbuf  = c3u + (size_t)BGRAPH * 128;
    float* d2buf = dbuf + (size_t)BGRAPH * 128;
    float* zbuf  = d2buf + (size_t)BGRAPH * 128;
    float* f1o   = zbuf + (size_t)BGRAPH * 256;
    float* f2o   = f1o + (size_t)BGRAPH * 128;
    float* pbuf  = aux;

    zero_buf<<<(10 * 1032 + 255) / 256, 256, 0, stream>>>(sb, 10 * 1032);
    transpose_w<<<(ta.total + 255) / 256, 256, 0, stream>>>(ta);

    // ================= GIN branch (in-place in `big`) ========================
    gin_agg<<<BGRAPH, 128, (2 * 32 * 9 + 2 * 9) * sizeof(float), stream>>>(
        drug_x, src, dst, aux, 9, nullptr, 0.f, 0);
    gemm_mfma<128><<<dim3(NNODE / 128, 1), 256, 0, stream>>>(
        aux, wt_g11, g11b, big, NNODE, 9, 128, nullptr, 0.f, 0, st_u1, 1, 0);
    gemm_mfma<128><<<dim3(NNODE / 128, 1), 256, 0, stream>>>(
        big, wt_g12, g12b, big, NNODE, 128, 128, st_u1, INV_N, 1, st_u2rel, 2, 0);
    gin_agg<<<BGRAPH, 128, (2 * 32 * 128 + 2 * 128) * sizeof(float), stream>>>(
        big, src, dst, big, 128, st_u2rel, INV_N, 3);
    gemm_mfma<128><<<dim3(NNODE / 128, 1), 256, 0, stream>>>(
        big, wt_g21, g21b, big, NNODE, 128, 128, nullptr, 0.f, 0, st_u3, 1, 0);
    gemm_mfma<128><<<dim3(NNODE / 128, 1), 256, 0, stream>>>(
        big, wt_g22, g22b, big, NNODE, 128, 128, st_u3, INV_N, 1, st_u4rel, 2, 0);
    pool_max<<<BGRAPH, 128, 0, stream>>>(big, pbuf, st_u4rel, INV_N);

    // ================= cell branch ===========================================
    gemm_mfma<128><<<dim3(BGRAPH / 128, 5), 256, 0, stream>>>(
        cell, wt_ce1, ce1b, c1, BGRAPH, CELLD, 516, nullptr, 0.f, 0, st_c1, 1, 0);
    gemm_mfma<128><<<dim3(BGRAPH / 128, 2), 256, 0, stream>>>(
        c1, wt_ce2, ce2b, c2, BGRAPH, 516, 256, st_c1, INV_B, 1, st_c2, 1, 0);
    gemm_mfma<128><<<dim3(BGRAPH / 128, 1), 256, 0, stream>>>(
        c2, wt_ce3, ce3b, c3u, BGRAPH, 256, 128, st_c2, INV_B, 1, st_c3, 1, 0);

    // ================= d branch ==============================================
    gemm_mfma<128><<<dim3(BGRAPH / 128, 1), 256, 0, stream>>>(
        pbuf, wt_d1, d1b, dbuf, BGRAPH, 128, 128, nullptr, 0.f, 0, st_d1, 1, 0);
    gemm_mfma<128><<<dim3(BGRAPH / 128, 1), 256, 0, stream>>>(
        dbuf, wt_d2, d2b, d2buf, BGRAPH, 128, 128, st_d1, INV_B, 1, nullptr, 0, 1);

    // ================= head ==================================================
    concat2<<<(BGRAPH * 256 + 255) / 256, 256, 0, stream>>>(
        c3u, d2buf, zbuf, st_c3, INV_B);
    gemm_mfma<128><<<dim3(BGRAPH / 128, 1), 256, 0, stream>>>(
        zbuf, wt_f1, f1b, f1o, BGRAPH, 256, 128, nullptr, 0.f, 0, st_f1, 1, 0);
    gemm_mfma<64><<<dim3(BGRAPH / 128, 1), 256, 0, stream>>>(
        f1o, wt_f2, f2b, f2o, BGRAPH, 128, 64, st_f1, INV_B, 2, st_f2, 1, 0);
    final_dot<<<BGRAPH / 256, 256, 0, stream>>>(f2o, f3w, f3b, out, st_f2, INV_B);
}